// Round 8
// baseline (162.770 us; speedup 1.0000x reference)
//
#include <hip/hip_runtime.h>
#include <stdint.h>

#define NODE_NUM 8192
#define NN 8384        // total nodes per graph (8384 = 131*64)
#define CC 128         // channels
#define BB 2           // batch
#define EE 262144      // edges per graph (2^18)
#define CAP 128        // global bucket stride per (node,kind)
#define CAP2 120       // LDS bucket capacity (max degree ~60, Poisson lambda~31)
#define P_B 131        // partitions per batch, 64 nodes each (131*64 = 8384)
#define NCHUNK 128     // edge chunks per batch (128 * 2048 = 2^18 edges)
#define RUNL 48        // slots per (partition,chunk); no overflow on this dataset
#define FILLB 256      // fill blocks (BB * NCHUNK)
#define IREPS 4        // MEASUREMENT: in-kernel reps for k_init (idempotent
                       // since R6: deterministic slots). Surfaces k_init in
                       // top-5 -> init_w = profiled/4. g4 is also DUPLICATED:
                       // adds g4_w(~10us known) + B -> per-boundary cost B =
                       // (dur-145.4) - 3*init_w - 10. Pre-committed rules:
                       // B>=8 -> re-fuse front without occupancy mistake;
                       // B<=4 -> fixed cost is cold/graph-intrinsic.
// Ledger: warm bucket+4gathers ~39-42us (R4); gathers per-node-bound (~10us
// each, intra==inter); R6 base 145.4. R7: flag-fused front +12.5 (spin + LDS
// union dropped proj occupancy 8->5 blk/CU). R1: no grid barriers.

__device__ __forceinline__ unsigned int f2bf_u(float f) {
  unsigned int u = __float_as_uint(f);
  return (u + 0x7FFFu + ((u >> 16) & 1u)) >> 16;
}
__device__ __forceinline__ float bf2f(unsigned int u) {
  return __uint_as_float(u << 16);
}
__device__ __forceinline__ float fast_tanh(float x) {
  float t = __expf(2.0f * x);
  return 1.0f - 2.0f * __builtin_amdgcn_rcpf(t + 1.0f);
}

// ---- K1: edge partitioning (deterministic chunk slots, coalesced flush) +
// bf16 pack + layer-1 projections. reps>1 repeats the WHOLE body (idempotent). ----
__global__ void k_init(const int* __restrict__ ei,
                       unsigned int* __restrict__ partBuf, unsigned char* __restrict__ cnt8,
                       const float* __restrict__ x, unsigned int* __restrict__ xb,
                       const float* __restrict__ Wi_s, const float* __restrict__ Wj_s,
                       const float* __restrict__ Wi_t, const float* __restrict__ Wj_t,
                       float* __restrict__ pi, float2* __restrict__ pjn,
                       int reps) {
  int tid = threadIdx.x;
  for (int r = 0; r < reps; ++r) {
    asm volatile("" ::: "memory");           // force true re-execution
    if (blockIdx.x < FILLB) {
      __shared__ unsigned int sEdge[2048];
      __shared__ int sCnt[P_B];
      __shared__ int sOff[P_B + 1];
      int b = blockIdx.x >> 7;               // NCHUNK==128 blocks per batch
      int chunk = blockIdx.x & (NCHUNK - 1);
      int e0 = chunk * 2048;
      const int* eb = ei + b * 2 * EE;
      for (int i = tid; i < P_B; i += 256) sCnt[i] = 0;
      __syncthreads();
      const int4* s4 = (const int4*)(eb + e0 + tid * 8);
      const int4* d4 = (const int4*)(eb + EE + e0 + tid * 8);
      int4 sa = s4[0], sb_ = s4[1], da = d4[0], db_ = d4[1];
      int srcs[8] = {sa.x, sa.y, sa.z, sa.w, sb_.x, sb_.y, sb_.z, sb_.w};
      int dsts[8] = {da.x, da.y, da.z, da.w, db_.x, db_.y, db_.z, db_.w};
      unsigned int cache[8];
#pragma unroll
      for (int k = 0; k < 8; ++k) {
        int src = srcs[k], dst = dsts[k];
        if ((unsigned)src >= NN || (unsigned)dst >= NN) { cache[k] = 0xFFFFFFFFu; continue; }
        int p = dst >> 6;
        cache[k] = ((unsigned)p << 20) | ((unsigned)(dst & 63) << 14) | (unsigned)src;
        atomicAdd(&sCnt[p], 1);
      }
      __syncthreads();
      if (tid == 0) {                        // serial prefix over 131 entries
        int acc = 0;
        for (int i = 0; i < P_B; ++i) { sOff[i] = acc; acc += sCnt[i]; }
        sOff[P_B] = acc;
      }
      __syncthreads();
      if (tid < P_B) sCnt[tid] = 0;          // reuse as placement cursor
      __syncthreads();
#pragma unroll
      for (int k = 0; k < 8; ++k) {
        unsigned int v = cache[k];
        if (v == 0xFFFFFFFFu) continue;
        int p = v >> 20;
        int pos = atomicAdd(&sCnt[p], 1);
        sEdge[sOff[p] + pos] = v;
      }
      __syncthreads();
      int total = sOff[P_B];
      for (int i = tid; i < total; i += 256) {   // coalesced partition runs
        unsigned int v = sEdge[i];
        int p = v >> 20;
        int idx = i - sOff[p];
        if (idx < RUNL)
          partBuf[(size_t)((b * P_B + p) * NCHUNK + chunk) * RUNL + idx] =
              v & 0xFFFFFu;                  // off|src, 20 bits
      }
      if (tid < P_B) {
        int c = sCnt[tid];
        cnt8[(b * P_B + tid) * NCHUNK + chunk] = (unsigned char)(c < RUNL ? c : RUNL);
      }
      __syncthreads();                       // protect LDS reuse across reps
    } else {
      int wid = ((blockIdx.x - FILLB) * blockDim.x + tid) >> 6;  // b*NN+n
      int lane = tid & 63;
      int n = wid % NN;
      bool is_s = (n < NODE_NUM);
      const float* wi = is_s ? Wi_s : Wi_t;
      const float* wj = is_s ? Wj_s : Wj_t;
      size_t oi = (size_t)wid * (CC / 2) + lane;
      float2 hv = ((const float2*)x)[oi];
      xb[oi] = (f2bf_u(hv.y) << 16) | f2bf_u(hv.x);
      float2 wiv = *(const float2*)(wi + lane * 2);
      float2 wjv = *(const float2*)(wj + lane * 2);
      float a = hv.x * wiv.x + hv.y * wiv.y;
      float c = hv.x * wjv.x + hv.y * wjv.y;
#pragma unroll
      for (int o = 32; o > 0; o >>= 1) {
        a += __shfl_xor(a, o, 64);
        c += __shfl_xor(c, o, 64);
      }
      if (lane == 0) { pi[wid] = a; pjn[wid].x = c; }
    }
  }
}

// ---- K2: per-HALF-partition bucket build + cnt-bounded dump + norms ----
__global__ void k_bucket(const unsigned int* __restrict__ partBuf,
                         const unsigned char* __restrict__ cnt8,
                         int* __restrict__ cur_intra, int* __restrict__ cur_inter,
                         int* __restrict__ colS_intra, int* __restrict__ colS_inter,
                         float* __restrict__ dinv_intra, float* __restrict__ selfnorm,
                         float* __restrict__ dinv_inter, float2* __restrict__ pjn0) {
  __shared__ unsigned int sIn[32 * CAP2];
  __shared__ unsigned int sIt[32 * CAP2];
  __shared__ int sC[64];                     // [0..31] intra, [32..63] inter
  __shared__ unsigned char sN[NCHUNK];
  int tid = threadIdx.x;
  int gp = blockIdx.x >> 1;                  // 0..261
  int half = blockIdx.x & 1;
  int b = gp / P_B;
  int p = gp - b * P_B;
  if (tid < 64) sC[tid] = 0;
  if (tid < NCHUNK) sN[tid] = cnt8[gp * NCHUNK + tid];
  __syncthreads();
  const unsigned int* buf = partBuf + (size_t)gp * (NCHUNK * RUNL);
  for (int s = tid; s < NCHUNK * RUNL; s += 256) {
    int c = s / RUNL;                        // magic-mul division
    int k = s - c * RUNL;
    if (k >= (int)sN[c]) continue;           // skip before the load
    unsigned int v = buf[s];
    int off = (v >> 14) & 63;
    if ((off >> 5) != half) continue;
    int o = off & 31;
    int src = v & 0x3FFF;
    int dst = p * 64 + off;
    bool ss = (src < NODE_NUM) && (dst < NODE_NUM);
    bool tt = (src >= NODE_NUM) && (dst >= NODE_NUM);
    if (ss || tt) {
      int pos = atomicAdd(&sC[o], 1);
      if (pos < CAP2) sIn[o * CAP2 + pos] = src;
    } else {
      int pos = atomicAdd(&sC[32 + o], 1);
      if (pos < CAP2) sIt[o * CAP2 + pos] = src;
    }
  }
  __syncthreads();
  int dbase = p * 64 + half * 32;
  size_t gbase = ((size_t)b * NN + dbase) * CAP;
  for (int j = tid; j < 32 * CAP; j += 256) {   // cnt-bounded dump (~31/128)
    int off = j >> 7, slot = j & (CAP - 1);
    int ci = sC[off];      ci = ci < CAP2 ? ci : CAP2;
    int ct = sC[32 + off]; ct = ct < CAP2 ? ct : CAP2;
    if (slot < ci) colS_intra[gbase + j] = (int)sIn[off * CAP2 + slot];
    if (slot < ct) colS_inter[gbase + j] = (int)sIt[off * CAP2 + slot];
  }
  if (tid < 32) {
    int node = b * NN + dbase + tid;
    int ci = sC[tid];       ci = ci < CAP2 ? ci : CAP2;
    int ct = sC[32 + tid];  ct = ct < CAP2 ? ct : CAP2;
    cur_intra[node] = ci;
    cur_inter[node] = ct;
    float df = (float)(ci + 1);             // gcn_norm adds a self loop
    float di = rsqrtf(df);
    dinv_intra[node] = di;
    selfnorm[node] = 1.0f / df;
    dinv_inter[node] = (ct > 0) ? (1.0f / (float)ct) : 0.0f;
    pjn0[node].y = di;                      // pair layer-1 pj with its src-norm
  }
}

// ---- gather: unchanged from R6 ----
template <bool INTRA, bool RELU, bool NEXTPROJ, bool NEXT_INTRA>
__global__ void __launch_bounds__(256, 6)
k_gather(const float* __restrict__ h_in, const unsigned int* __restrict__ hm,
         float* __restrict__ h_out, unsigned int* __restrict__ hm_out,
         const int* __restrict__ cnt, const int* __restrict__ colS,
         const float* __restrict__ pi, const float2* __restrict__ pjn,
         const float* __restrict__ normD, const float* __restrict__ selfnorm,
         const float* __restrict__ dinv_intra,
         const float* __restrict__ nWi_s, const float* __restrict__ nWj_s,
         const float* __restrict__ nWi_t, const float* __restrict__ nWj_t,
         float* __restrict__ pi_out, float2* __restrict__ pjn_out) {
  int wid = (blockIdx.x * blockDim.x + threadIdx.x) >> 6;
  int lane = threadIdx.x & 63;
  int b = wid >= NN;
  int n = wid - b * NN;
  int mt = cnt[wid];
  mt = mt < CAP ? mt : CAP;
  const unsigned int* hmb = hm + (size_t)b * NN * (CC / 2) + lane;
  const float2* pjnb = pjn + b * NN;
  float p_i = pi[wid];
  float nd = normD[wid];
  const float2 hv = *(const float2*)(h_in + (size_t)wid * CC + lane * 2);
  float2 acc;
  if (INTRA) {
    float fac = 1.0f + fast_tanh(p_i + pjnb[n].x) * selfnorm[wid];
    acc.x = hv.x * fac;
    acc.y = hv.y * fac;
  } else {
    acc = hv;  // residual only
  }
  const int* cS = colS + (size_t)wid * CAP;
  for (int off = 0; off < mt; off += 64) {
    int rem = mt - off;
    int m = rem < 64 ? rem : 64;
    int src = 0;
    float c = 0.0f;
    if (lane < m) {
      src = cS[off + lane];
      float2 pn = pjnb[src];                 // one 8B random gather per edge
      float a = fast_tanh(p_i + pn.x);
      c = a * nd;
      if (INTRA) c *= pn.y;
    }
#pragma unroll
    for (int base = 0; base < 64; base += 16) {
      if (base >= m) break;
      unsigned int u16[16];
      float cj[16];
#pragma unroll
      for (int k = 0; k < 16; ++k) {
        int sj = __builtin_amdgcn_readlane(src, base + k);           // SGPR
        cj[k] = __int_as_float(
            __builtin_amdgcn_readlane(__float_as_int(c), base + k)); // SGPR
        u16[k] = hmb[sj * (CC / 2)];   // saddr-form load, 16 in flight
      }
#pragma unroll
      for (int k = 0; k < 16; ++k) {
        acc.x = fmaf(bf2f(u16[k] & 0xFFFFu), cj[k], acc.x);
        acc.y = fmaf(bf2f(u16[k] >> 16), cj[k], acc.y);
      }
    }
  }
  if (RELU) { acc.x = fmaxf(acc.x, 0.0f); acc.y = fmaxf(acc.y, 0.0f); }
  size_t oi = (size_t)wid * (CC / 2) + lane;
  *(float2*)(h_out + 2 * oi) = acc;
  if (NEXTPROJ) {
    hm_out[oi] = (f2bf_u(acc.y) << 16) | f2bf_u(acc.x);
    bool is_s = (n < NODE_NUM);
    const float* wi = is_s ? nWi_s : nWi_t;
    const float* wj = is_s ? nWj_s : nWj_t;
    float2 wiv = *(const float2*)(wi + lane * 2);
    float2 wjv = *(const float2*)(wj + lane * 2);
    float a = acc.x * wiv.x + acc.y * wiv.y;
    float c2 = acc.x * wjv.x + acc.y * wjv.y;
#pragma unroll
    for (int o = 32; o > 0; o >>= 1) {
      a += __shfl_xor(a, o, 64);
      c2 += __shfl_xor(c2, o, 64);
    }
    if (lane == 0) {
      pi_out[wid] = a;
      float2 pn;
      pn.x = c2;
      pn.y = NEXT_INTRA ? dinv_intra[wid] : 0.0f;
      pjn_out[wid] = pn;
    }
  }
}

extern "C" void kernel_launch(void* const* d_in, const int* in_sizes, int n_in,
                              void* d_out, int out_size, void* d_ws, size_t ws_size,
                              hipStream_t stream) {
  const float* x = (const float*)d_in[0];      // fp32 features [B,N,C]
  const int* ei = (const int*)d_in[1];         // int32 [B,2,E]
  const float* Wss = (const float*)d_in[2];    // fp32 [2, 2C]
  const float* Wtt = (const float*)d_in[3];
  const float* Wst = (const float*)d_in[4];
  const float* Wts = (const float*)d_in[5];
  float* out = (float*)d_out;                  // fp32 output [B,N,C]

  char* p = (char*)d_ws;
  auto alloc = [&](size_t bytes) {
    void* r = (void*)p;
    p += ((bytes + 255) & ~(size_t)255);
    return r;
  };
  float* h0 = (float*)alloc((size_t)BB * NN * CC * 4);
  float* h1 = (float*)alloc((size_t)BB * NN * CC * 4);
  unsigned int* xb = (unsigned int*)alloc((size_t)BB * NN * CC * 2);  // bf16 mirrors
  unsigned int* mb0 = (unsigned int*)alloc((size_t)BB * NN * CC * 2);
  unsigned int* mb1 = (unsigned int*)alloc((size_t)BB * NN * CC * 2);
  float* pi0 = (float*)alloc(BB * NN * 4);
  float* pi1 = (float*)alloc(BB * NN * 4);
  float2* pjn0 = (float2*)alloc(BB * NN * 8);   // paired {pj, src-norm}
  float2* pjn1 = (float2*)alloc(BB * NN * 8);
  float* dinv_intra = (float*)alloc(BB * NN * 4);
  float* selfnorm = (float*)alloc(BB * NN * 4);
  float* dinv_inter = (float*)alloc(BB * NN * 4);
  int* cur_intra = (int*)alloc(BB * NN * 4);
  int* cur_inter = (int*)alloc(BB * NN * 4);
  int* colS_intra = (int*)alloc((size_t)BB * NN * CAP * 4);  // 8.6 MB buckets
  int* colS_inter = (int*)alloc((size_t)BB * NN * CAP * 4);
  unsigned char* cnt8 = (unsigned char*)alloc(BB * P_B * NCHUNK);  // 33.5 KB
  unsigned int* partBuf = (unsigned int*)alloc((size_t)BB * P_B * NCHUNK * RUNL * 4);  // 6.4 MB

  const int NODE_BLOCKS = (BB * NN * 64) / 256;  // 1 wave per node, 4 waves/block
  const float* wss0 = Wss, *wtt0 = Wtt, *wst0 = Wst, *wts0 = Wts;
  const float* wss1 = Wss + 256, *wtt1 = Wtt + 256, *wst1 = Wst + 256, *wts1 = Wts + 256;

  // K1 (edge partition + pack + layer-1 proj), IREPS for attribution
  k_init<<<FILLB + NODE_BLOCKS, 256, 0, stream>>>(
      ei, partBuf, cnt8, x, xb, wss0, wss0 + 128, wtt0, wtt0 + 128, pi0, pjn0, IREPS);
  // K2 (bucket build, cnt-bounded dump, norms, pjn0.y)
  k_bucket<<<BB * P_B * 2, 256, 0, stream>>>(partBuf, cnt8, cur_intra, cur_inter,
                                             colS_intra, colS_inter,
                                             dinv_intra, selfnorm, dinv_inter, pjn0);

  // layer 1 (intra, relu): (x,xb) -> (h0,mb0); fused proj for layer 2 (inter)
  k_gather<true, true, true, false><<<NODE_BLOCKS, 256, 0, stream>>>(
      x, xb, h0, mb0, cur_intra, colS_intra, pi0, pjn0, dinv_intra, selfnorm, dinv_intra,
      wts0, wst0 + 128, wst0, wts0 + 128, pi1, pjn1);

  // layer 2 (inter, relu): (h0,mb0) -> (h1,mb1); fused proj for layer 3 (intra)
  k_gather<false, true, true, true><<<NODE_BLOCKS, 256, 0, stream>>>(
      h0, mb0, h1, mb1, cur_inter, colS_inter, pi1, pjn1, dinv_inter, selfnorm, dinv_intra,
      wss1, wss1 + 128, wtt1, wtt1 + 128, pi0, pjn0);

  // layer 3 (intra, relu): (h1,mb1) -> (h0,mb0); fused proj for layer 4 (inter)
  k_gather<true, true, true, false><<<NODE_BLOCKS, 256, 0, stream>>>(
      h1, mb1, h0, mb0, cur_intra, colS_intra, pi0, pjn0, dinv_intra, selfnorm, dinv_intra,
      wts1, wst1 + 128, wst1, wts1 + 128, pi1, pjn1);

  // layer 4 (inter, no relu): (h0,mb0) -> d_out; no next proj
  k_gather<false, false, false, false><<<NODE_BLOCKS, 256, 0, stream>>>(
      h0, mb0, out, nullptr, cur_inter, colS_inter, pi1, pjn1, dinv_inter, selfnorm,
      dinv_intra, nullptr, nullptr, nullptr, nullptr, nullptr, nullptr);

  // MEASUREMENT: duplicate g4 (byte-identical output). Adds g4_w + B.
  k_gather<false, false, false, false><<<NODE_BLOCKS, 256, 0, stream>>>(
      h0, mb0, out, nullptr, cur_inter, colS_inter, pi1, pjn1, dinv_inter, selfnorm,
      dinv_intra, nullptr, nullptr, nullptr, nullptr, nullptr, nullptr);
}

// Round 9
// 147.556 us; speedup vs baseline: 1.1031x; 1.1031x over previous
//
#include <hip/hip_runtime.h>
#include <stdint.h>

#define NODE_NUM 8192
#define NN 8384        // total nodes per graph (8384 = 131*64)
#define CC 128         // channels
#define BB 2           // batch
#define EE 262144      // edges per graph (2^18)
#define CAP 128        // global bucket stride per (node,kind)
#define CAP2 120       // LDS bucket capacity (max degree ~60, Poisson lambda~31)
#define P_B 131        // partitions per batch, 64 nodes each (131*64 = 8384)
#define NCHUNK 128     // edge chunks per batch (128 * 2048 = 2^18 edges)
#define RUNL 48        // slots per (partition,chunk); no overflow on this dataset
#define FILLB 256      // fill blocks (BB * NCHUNK)
// Ledger (R4/R8 total-time algebra): init_w~2.5, bucket~5, gathers ~8-10 each
// (per-WAVE fixed-cost bound: intra==inter despite 40x edges), boundary B~2us
// -> boundaries are NOT the lever (R7 fusion refuted). ~88us of the 145 is
// cold/harness-intrinsic (unattributed after 5 probes). R9: sparse L4 over
// compacted inter-dst list (L3 writes `out` directly; ~8.8K of 16768 waves
// survive) + packed float4 node params. Both bit-identical to dense path.
// R1: no grid barriers. R5: keep coalesced fill flush + 1 node/wave TLP.

__device__ __forceinline__ unsigned int f2bf_u(float f) {
  unsigned int u = __float_as_uint(f);
  return (u + 0x7FFFu + ((u >> 16) & 1u)) >> 16;
}
__device__ __forceinline__ float bf2f(unsigned int u) {
  return __uint_as_float(u << 16);
}
__device__ __forceinline__ float fast_tanh(float x) {
  float t = __expf(2.0f * x);
  return 1.0f - 2.0f * __builtin_amdgcn_rcpf(t + 1.0f);
}

// ---- K1: edge partitioning (deterministic chunk slots, coalesced flush) +
// bf16 pack + layer-1 projections into prmA.xy / pjn0.x ----
__global__ void k_init(const int* __restrict__ ei,
                       unsigned int* __restrict__ partBuf, unsigned char* __restrict__ cnt8,
                       const float* __restrict__ x, unsigned int* __restrict__ xb,
                       const float* __restrict__ Wi_s, const float* __restrict__ Wj_s,
                       const float* __restrict__ Wi_t, const float* __restrict__ Wj_t,
                       float4* __restrict__ prmA, float2* __restrict__ pjn,
                       int* __restrict__ nInter) {
  int tid = threadIdx.x;
  if (blockIdx.x < FILLB) {
    __shared__ unsigned int sEdge[2048];
    __shared__ int sCnt[P_B];
    __shared__ int sOff[P_B + 1];
    int b = blockIdx.x >> 7;                 // NCHUNK==128 blocks per batch
    int chunk = blockIdx.x & (NCHUNK - 1);
    int e0 = chunk * 2048;
    const int* eb = ei + b * 2 * EE;
    for (int i = tid; i < P_B; i += 256) sCnt[i] = 0;
    __syncthreads();
    const int4* s4 = (const int4*)(eb + e0 + tid * 8);
    const int4* d4 = (const int4*)(eb + EE + e0 + tid * 8);
    int4 sa = s4[0], sb_ = s4[1], da = d4[0], db_ = d4[1];
    int srcs[8] = {sa.x, sa.y, sa.z, sa.w, sb_.x, sb_.y, sb_.z, sb_.w};
    int dsts[8] = {da.x, da.y, da.z, da.w, db_.x, db_.y, db_.z, db_.w};
    unsigned int cache[8];
#pragma unroll
    for (int k = 0; k < 8; ++k) {
      int src = srcs[k], dst = dsts[k];
      if ((unsigned)src >= NN || (unsigned)dst >= NN) { cache[k] = 0xFFFFFFFFu; continue; }
      int p = dst >> 6;
      cache[k] = ((unsigned)p << 20) | ((unsigned)(dst & 63) << 14) | (unsigned)src;
      atomicAdd(&sCnt[p], 1);
    }
    __syncthreads();
    if (tid == 0) {                          // serial prefix over 131 entries
      int acc = 0;
      for (int i = 0; i < P_B; ++i) { sOff[i] = acc; acc += sCnt[i]; }
      sOff[P_B] = acc;
    }
    __syncthreads();
    if (tid < P_B) sCnt[tid] = 0;            // reuse as placement cursor
    __syncthreads();
#pragma unroll
    for (int k = 0; k < 8; ++k) {
      unsigned int v = cache[k];
      if (v == 0xFFFFFFFFu) continue;
      int p = v >> 20;
      int pos = atomicAdd(&sCnt[p], 1);
      sEdge[sOff[p] + pos] = v;
    }
    __syncthreads();
    int total = sOff[P_B];
    for (int i = tid; i < total; i += 256) {   // coalesced partition runs
      unsigned int v = sEdge[i];
      int p = v >> 20;
      int idx = i - sOff[p];
      if (idx < RUNL)
        partBuf[(size_t)((b * P_B + p) * NCHUNK + chunk) * RUNL + idx] =
            v & 0xFFFFFu;                    // off|src, 20 bits
    }
    if (tid < P_B) {
      int c = sCnt[tid];
      cnt8[(b * P_B + tid) * NCHUNK + chunk] = (unsigned char)(c < RUNL ? c : RUNL);
    }
  } else {
    if (blockIdx.x == FILLB && tid == 0) *nInter = 0;  // reset sparse counter
    int wid = ((blockIdx.x - FILLB) * blockDim.x + tid) >> 6;  // b*NN+n
    int lane = tid & 63;
    int n = wid % NN;
    bool is_s = (n < NODE_NUM);
    const float* wi = is_s ? Wi_s : Wi_t;
    const float* wj = is_s ? Wj_s : Wj_t;
    size_t oi = (size_t)wid * (CC / 2) + lane;
    float2 hv = ((const float2*)x)[oi];
    xb[oi] = (f2bf_u(hv.y) << 16) | f2bf_u(hv.x);
    float2 wiv = *(const float2*)(wi + lane * 2);
    float2 wjv = *(const float2*)(wj + lane * 2);
    float a = hv.x * wiv.x + hv.y * wiv.y;
    float c = hv.x * wjv.x + hv.y * wjv.y;
#pragma unroll
    for (int o = 32; o > 0; o >>= 1) {
      a += __shfl_xor(a, o, 64);
      c += __shfl_xor(c, o, 64);
    }
    if (lane == 0) {
      ((float2*)(prmA + wid))[0] = make_float2(a, c);  // prmA.xy = {pi, pj}
      pjn[wid].x = c;
    }
  }
}

// ---- K2: per-HALF-partition bucket build + cnt-bounded dump + norms into
// prmA.zw (intra: {dinv,selfnorm}) / prmB.zw (inter: {dinv,0}) + pjn0.y +
// compacted inter-dst list for sparse layer 4 ----
__global__ void k_bucket(const unsigned int* __restrict__ partBuf,
                         const unsigned char* __restrict__ cnt8,
                         int* __restrict__ cur_intra, int* __restrict__ cur_inter,
                         int* __restrict__ colS_intra, int* __restrict__ colS_inter,
                         float* __restrict__ dinv_intra,
                         float4* __restrict__ prmA, float4* __restrict__ prmB,
                         float2* __restrict__ pjn0,
                         int* __restrict__ interList, int* __restrict__ nInter) {
  __shared__ unsigned int sIn[32 * CAP2];
  __shared__ unsigned int sIt[32 * CAP2];
  __shared__ int sC[64];                     // [0..31] intra, [32..63] inter
  __shared__ unsigned char sN[NCHUNK];
  int tid = threadIdx.x;
  int gp = blockIdx.x >> 1;                  // 0..261
  int half = blockIdx.x & 1;
  int b = gp / P_B;
  int p = gp - b * P_B;
  if (tid < 64) sC[tid] = 0;
  if (tid < NCHUNK) sN[tid] = cnt8[gp * NCHUNK + tid];
  __syncthreads();
  const unsigned int* buf = partBuf + (size_t)gp * (NCHUNK * RUNL);
  for (int s = tid; s < NCHUNK * RUNL; s += 256) {
    int c = s / RUNL;                        // magic-mul division
    int k = s - c * RUNL;
    if (k >= (int)sN[c]) continue;           // skip before the load
    unsigned int v = buf[s];
    int off = (v >> 14) & 63;
    if ((off >> 5) != half) continue;
    int o = off & 31;
    int src = v & 0x3FFF;
    int dst = p * 64 + off;
    bool ss = (src < NODE_NUM) && (dst < NODE_NUM);
    bool tt = (src >= NODE_NUM) && (dst >= NODE_NUM);
    if (ss || tt) {
      int pos = atomicAdd(&sC[o], 1);
      if (pos < CAP2) sIn[o * CAP2 + pos] = src;
    } else {
      int pos = atomicAdd(&sC[32 + o], 1);
      if (pos < CAP2) sIt[o * CAP2 + pos] = src;
    }
  }
  __syncthreads();
  int dbase = p * 64 + half * 32;
  size_t gbase = ((size_t)b * NN + dbase) * CAP;
  for (int j = tid; j < 32 * CAP; j += 256) {   // cnt-bounded dump (~31/128)
    int off = j >> 7, slot = j & (CAP - 1);
    int ci = sC[off];      ci = ci < CAP2 ? ci : CAP2;
    int ct = sC[32 + off]; ct = ct < CAP2 ? ct : CAP2;
    if (slot < ci) colS_intra[gbase + j] = (int)sIn[off * CAP2 + slot];
    if (slot < ct) colS_inter[gbase + j] = (int)sIt[off * CAP2 + slot];
  }
  if (tid < 32) {
    int node = b * NN + dbase + tid;
    int ci = sC[tid];       ci = ci < CAP2 ? ci : CAP2;
    int ct = sC[32 + tid];  ct = ct < CAP2 ? ct : CAP2;
    cur_intra[node] = ci;
    cur_inter[node] = ct;
    float df = (float)(ci + 1);             // gcn_norm adds a self loop
    float di = rsqrtf(df);
    dinv_intra[node] = di;
    float dt = (ct > 0) ? (1.0f / (float)ct) : 0.0f;
    ((float2*)(prmA + node))[1] = make_float2(di, 1.0f / df);  // {nd, selfnorm}
    ((float2*)(prmB + node))[1] = make_float2(dt, 0.0f);       // {nd, -}
    pjn0[node].y = di;                      // pair layer-1 pj with its src-norm
    if (ct > 0) {                           // compacted list for sparse L4
      int pos = atomicAdd(nInter, 1);
      interList[pos] = node;
    }
  }
}

// ---- gather: packed float4 params {pi,pj,nd,sn} (one load), fused edge
// coefs (fast_tanh), bf16 messages, readlane broadcast, 16-deep load groups,
// fused next-layer projection. SPARSE: wid from compacted inter-dst list,
// in-place row update (used for layer 4). ----
template <bool INTRA, bool RELU, bool NEXTPROJ, bool NEXT_INTRA, bool SPARSE>
__global__ void __launch_bounds__(256, 6)
k_gather(const float* __restrict__ h_in, const unsigned int* __restrict__ hm,
         float* __restrict__ h_out, unsigned int* __restrict__ hm_out,
         const int* __restrict__ cnt, const int* __restrict__ colS,
         const float4* __restrict__ prm, const float2* __restrict__ pjn,
         const float* __restrict__ dinv_intra,
         const float* __restrict__ nWi_s, const float* __restrict__ nWj_s,
         const float* __restrict__ nWi_t, const float* __restrict__ nWj_t,
         float4* __restrict__ prm_out, float2* __restrict__ pjn_out,
         const int* __restrict__ interList, const int* __restrict__ nInter) {
  int gwave = (blockIdx.x * blockDim.x + threadIdx.x) >> 6;
  int wid;
  if (SPARSE) {
    if (gwave >= *nInter) return;            // dead waves retire immediately
    wid = interList[gwave];
  } else {
    wid = gwave;
  }
  int lane = threadIdx.x & 63;
  int b = wid >= NN;
  int n = wid - b * NN;
  int mt = cnt[wid];
  mt = mt < CAP ? mt : CAP;
  const unsigned int* hmb = hm + (size_t)b * NN * (CC / 2) + lane;
  const float2* pjnb = pjn + b * NN;
  float4 pr = prm[wid];                      // {pi, pj_self, normD, selfnorm}
  float p_i = pr.x;
  float nd = pr.z;
  const float2 hv = *(const float2*)(h_in + (size_t)wid * CC + lane * 2);
  float2 acc;
  if (INTRA) {
    // residual + self-loop message: h * (1 + tanh(pi+pj)/deg)  (fp32 path)
    float fac = 1.0f + fast_tanh(p_i + pr.y) * pr.w;
    acc.x = hv.x * fac;
    acc.y = hv.y * fac;
  } else {
    acc = hv;  // residual only
  }
  const int* cS = colS + (size_t)wid * CAP;
  for (int off = 0; off < mt; off += 64) {
    int rem = mt - off;
    int m = rem < 64 ? rem : 64;
    int src = 0;
    float c = 0.0f;
    if (lane < m) {
      src = cS[off + lane];
      float2 pn = pjnb[src];                 // one 8B random gather per edge
      float a = fast_tanh(p_i + pn.x);
      c = a * nd;
      if (INTRA) c *= pn.y;
    }
#pragma unroll
    for (int base = 0; base < 64; base += 16) {
      if (base >= m) break;
      unsigned int u16[16];
      float cj[16];
#pragma unroll
      for (int k = 0; k < 16; ++k) {
        int sj = __builtin_amdgcn_readlane(src, base + k);           // SGPR
        cj[k] = __int_as_float(
            __builtin_amdgcn_readlane(__float_as_int(c), base + k)); // SGPR
        u16[k] = hmb[sj * (CC / 2)];   // saddr-form load, 16 in flight
      }
#pragma unroll
      for (int k = 0; k < 16; ++k) {
        acc.x = fmaf(bf2f(u16[k] & 0xFFFFu), cj[k], acc.x);
        acc.y = fmaf(bf2f(u16[k] >> 16), cj[k], acc.y);
      }
    }
  }
  if (RELU) { acc.x = fmaxf(acc.x, 0.0f); acc.y = fmaxf(acc.y, 0.0f); }
  size_t oi = (size_t)wid * (CC / 2) + lane;
  *(float2*)(h_out + 2 * oi) = acc;
  if (NEXTPROJ) {
    hm_out[oi] = (f2bf_u(acc.y) << 16) | f2bf_u(acc.x);
    bool is_s = (n < NODE_NUM);
    const float* wi = is_s ? nWi_s : nWi_t;
    const float* wj = is_s ? nWj_s : nWj_t;
    float2 wiv = *(const float2*)(wi + lane * 2);
    float2 wjv = *(const float2*)(wj + lane * 2);
    float a = acc.x * wiv.x + acc.y * wiv.y;
    float c2 = acc.x * wjv.x + acc.y * wjv.y;
#pragma unroll
    for (int o = 32; o > 0; o >>= 1) {
      a += __shfl_xor(a, o, 64);
      c2 += __shfl_xor(c2, o, 64);
    }
    if (lane == 0) {
      ((float2*)(prm_out + wid))[0] = make_float2(a, c2);  // .xy = {pi, pj}
      float2 pn;
      pn.x = c2;
      pn.y = NEXT_INTRA ? dinv_intra[wid] : 0.0f;
      pjn_out[wid] = pn;
    }
  }
}

extern "C" void kernel_launch(void* const* d_in, const int* in_sizes, int n_in,
                              void* d_out, int out_size, void* d_ws, size_t ws_size,
                              hipStream_t stream) {
  const float* x = (const float*)d_in[0];      // fp32 features [B,N,C]
  const int* ei = (const int*)d_in[1];         // int32 [B,2,E]
  const float* Wss = (const float*)d_in[2];    // fp32 [2, 2C]
  const float* Wtt = (const float*)d_in[3];
  const float* Wst = (const float*)d_in[4];
  const float* Wts = (const float*)d_in[5];
  float* out = (float*)d_out;                  // fp32 output [B,N,C]

  char* p = (char*)d_ws;
  auto alloc = [&](size_t bytes) {
    void* r = (void*)p;
    p += ((bytes + 255) & ~(size_t)255);
    return r;
  };
  float* h0 = (float*)alloc((size_t)BB * NN * CC * 4);
  float* h1 = (float*)alloc((size_t)BB * NN * CC * 4);
  unsigned int* xb = (unsigned int*)alloc((size_t)BB * NN * CC * 2);  // bf16 mirrors
  unsigned int* mb0 = (unsigned int*)alloc((size_t)BB * NN * CC * 2);
  unsigned int* mb1 = (unsigned int*)alloc((size_t)BB * NN * CC * 2);
  float4* prmA = (float4*)alloc(BB * NN * 16);  // packed {pi,pj,nd,sn}, intra
  float4* prmB = (float4*)alloc(BB * NN * 16);  // packed, inter
  float2* pjn0 = (float2*)alloc(BB * NN * 8);   // paired {pj, src-norm}
  float2* pjn1 = (float2*)alloc(BB * NN * 8);
  float* dinv_intra = (float*)alloc(BB * NN * 4);
  int* cur_intra = (int*)alloc(BB * NN * 4);
  int* cur_inter = (int*)alloc(BB * NN * 4);
  int* colS_intra = (int*)alloc((size_t)BB * NN * CAP * 4);  // 8.6 MB buckets
  int* colS_inter = (int*)alloc((size_t)BB * NN * CAP * 4);
  unsigned char* cnt8 = (unsigned char*)alloc(BB * P_B * NCHUNK);  // 33.5 KB
  int* interList = (int*)alloc(BB * NN * 4);   // compacted inter-dst nodes
  int* nInter = (int*)alloc(256);              // list length (reset by k_init)
  unsigned int* partBuf = (unsigned int*)alloc((size_t)BB * P_B * NCHUNK * RUNL * 4);  // 6.4 MB

  const int NODE_BLOCKS = (BB * NN * 64) / 256;  // 1 wave per node, 4 waves/block
  const float* wss0 = Wss, *wtt0 = Wtt, *wst0 = Wst, *wts0 = Wts;
  const float* wss1 = Wss + 256, *wtt1 = Wtt + 256, *wst1 = Wst + 256, *wts1 = Wts + 256;

  // K1 (edge partition + pack + layer-1 proj -> prmA.xy, pjn0.x; reset nInter)
  k_init<<<FILLB + NODE_BLOCKS, 256, 0, stream>>>(
      ei, partBuf, cnt8, x, xb, wss0, wss0 + 128, wtt0, wtt0 + 128,
      prmA, pjn0, nInter);
  // K2 (bucket build, cnt-bounded dump, norms -> prm*.zw, pjn0.y, interList)
  k_bucket<<<BB * P_B * 2, 256, 0, stream>>>(partBuf, cnt8, cur_intra, cur_inter,
                                             colS_intra, colS_inter, dinv_intra,
                                             prmA, prmB, pjn0, interList, nInter);

  // layer 1 (intra, relu): (x,xb) -> (h0,mb0); fused proj for layer 2 (inter)
  // inter proj: s-node pi=W_ts[:C], pj=W_st[C:]; t-node pi=W_st[:C], pj=W_ts[C:]
  k_gather<true, true, true, false, false><<<NODE_BLOCKS, 256, 0, stream>>>(
      x, xb, h0, mb0, cur_intra, colS_intra, prmA, pjn0, dinv_intra,
      wts0, wst0 + 128, wst0, wts0 + 128, prmB, pjn1, nullptr, nullptr);

  // layer 2 (inter, relu): (h0,mb0) -> (h1,mb1); fused proj for layer 3 (intra)
  k_gather<false, true, true, true, false><<<NODE_BLOCKS, 256, 0, stream>>>(
      h0, mb0, h1, mb1, cur_inter, colS_inter, prmB, pjn1, dinv_intra,
      wss1, wss1 + 128, wtt1, wtt1 + 128, prmA, pjn0, nullptr, nullptr);

  // layer 3 (intra, relu): (h1,mb1) -> (OUT, mb0); fused proj for layer 4
  // (writes `out` directly: layer 4 only touches inter-dst rows)
  k_gather<true, true, true, false, false><<<NODE_BLOCKS, 256, 0, stream>>>(
      h1, mb1, out, mb0, cur_intra, colS_intra, prmA, pjn0, dinv_intra,
      wts1, wst1 + 128, wst1, wts1 + 128, prmB, pjn1, nullptr, nullptr);

  // layer 4 (inter, no relu): SPARSE in-place update of `out` rows with
  // inter in-edges (~8.8K waves vs 16768; no dense copy)
  k_gather<false, false, false, false, true><<<NODE_BLOCKS, 256, 0, stream>>>(
      out, mb0, out, nullptr, cur_inter, colS_inter, prmB, pjn1, dinv_intra,
      nullptr, nullptr, nullptr, nullptr, nullptr, nullptr, interList, nInter);
}

// Round 10
// 142.051 us; speedup vs baseline: 1.1459x; 1.0388x over previous
//
#include <hip/hip_runtime.h>
#include <stdint.h>

#define NODE_NUM 8192
#define NN 8384        // total nodes per graph (8384 = 131*64)
#define CC 128         // channels
#define BB 2           // batch
#define EE 262144      // edges per graph (2^18)
#define CAP 128        // global bucket stride per (node,kind)
#define CAP2 120       // LDS bucket capacity (max degree ~60, Poisson lambda~31)
#define P_B 131        // partitions per batch, 64 nodes each (131*64 = 8384)
#define CAPP 4096      // partition buffer capacity (expected ~2000 +- 45)
#define FILLB 256      // phase-1 fill blocks (256 * 2048 = 2^19 edges)

// ---- REVERT to R3 (best measured: 143.9us) --------------------------------
// Closed ledger (R4/R8/R9 algebra): dur = ~88us harness poison fills (2x44us
// 256MB fills inside the timed region, untouchable) + ~39us warm work (intra
// gathers 2x~13us AT the L2-line-transaction roofline: 2 lines per 256B bf16
// message row, ~4 lines/cy/XCD) + ~12us boundaries (B~2us x6; R1/R7 proved
// in-kernel handoff costs more) + ~5us cold premium. Floor ~144us = measured
// plateau. Failed/null levers (do not retry): grid-barrier fusion (R1 +6x),
// flag-handoff fusion (R7 +12), fast_tanh (R6 null), sparse L4 + packed
// params (R9 +2), scalar-pj (R5 bundle regressed), batch-affine swizzle
// kept here (R3, -0.6 vs R2; within noise but best measured).

__device__ __forceinline__ unsigned int f2bf_u(float f) {
  unsigned int u = __float_as_uint(f);
  return (u + 0x7FFFu + ((u >> 16) & 1u)) >> 16;
}
__device__ __forceinline__ float bf2f(unsigned int u) {
  return __uint_as_float(u << 16);
}

// ---- phase 1: LDS-segmented edge partitioning (+ fused init for x) ----
__global__ void k_part_init(const int* __restrict__ ei,
                            int* __restrict__ partCur, unsigned int* __restrict__ partBuf,
                            const float* __restrict__ x, unsigned int* __restrict__ xb,
                            const float* __restrict__ Wi_s, const float* __restrict__ Wj_s,
                            const float* __restrict__ Wi_t, const float* __restrict__ Wj_t,
                            float* __restrict__ pi, float2* __restrict__ pjn) {
  if (blockIdx.x < FILLB) {
    __shared__ unsigned int sEdge[2048];
    __shared__ int sCnt[P_B];
    __shared__ int sOff[P_B + 1];
    __shared__ int sBase[P_B];
    int tid = threadIdx.x;
    int xcd = blockIdx.x & 7;
    int b = xcd >> 2;
    int e0 = ((xcd & 3) * 32 + (blockIdx.x >> 3)) * 2048;
    const int* eb = ei + b * 2 * EE;
    for (int i = tid; i < P_B; i += 256) sCnt[i] = 0;
    __syncthreads();
    const int4* s4 = (const int4*)(eb + e0 + tid * 8);
    const int4* d4 = (const int4*)(eb + EE + e0 + tid * 8);
    int4 sa = s4[0], sb_ = s4[1], da = d4[0], db_ = d4[1];
    int srcs[8] = {sa.x, sa.y, sa.z, sa.w, sb_.x, sb_.y, sb_.z, sb_.w};
    int dsts[8] = {da.x, da.y, da.z, da.w, db_.x, db_.y, db_.z, db_.w};
    unsigned int cache[8];
#pragma unroll
    for (int k = 0; k < 8; ++k) {
      int src = srcs[k], dst = dsts[k];
      if ((unsigned)src >= NN || (unsigned)dst >= NN) { cache[k] = 0xFFFFFFFFu; continue; }
      int p = dst >> 6;
      cache[k] = ((unsigned)p << 20) | ((unsigned)(dst & 63) << 14) | (unsigned)src;
      atomicAdd(&sCnt[p], 1);
    }
    __syncthreads();
    if (tid == 0) {                          // serial prefix over 131 entries
      int acc = 0;
      for (int i = 0; i < P_B; ++i) { sOff[i] = acc; acc += sCnt[i]; }
      sOff[P_B] = acc;
    }
    __syncthreads();
    if (tid < P_B) sBase[tid] = atomicAdd(&partCur[b * P_B + tid], sCnt[tid]);
    __syncthreads();
    if (tid < P_B) sCnt[tid] = 0;            // reuse as placement cursor
    __syncthreads();
#pragma unroll
    for (int k = 0; k < 8; ++k) {
      unsigned int v = cache[k];
      if (v == 0xFFFFFFFFu) continue;
      int p = v >> 20;
      int pos = atomicAdd(&sCnt[p], 1);
      sEdge[sOff[p] + pos] = v;
    }
    __syncthreads();
    int total = sOff[P_B];
    for (int i = tid; i < total; i += 256) {
      unsigned int v = sEdge[i];
      int p = v >> 20;
      int idx = (i - sOff[p]) + sBase[p];
      if (idx < CAPP)
        partBuf[(size_t)(b * P_B + p) * CAPP + idx] = v & 0xFFFFFu;  // off|src
    }
  } else {
    int j = blockIdx.x - FILLB;
    int xcd = j & 7;
    int b = xcd >> 2;
    int u = (xcd & 3) * 524 + (j >> 3);      // node-block within batch [0,2096)
    int wid = b * NN + u * 4 + (threadIdx.x >> 6);
    int lane = threadIdx.x & 63;
    int n = wid % NN;
    bool is_s = (n < NODE_NUM);
    const float* wi = is_s ? Wi_s : Wi_t;
    const float* wj = is_s ? Wj_s : Wj_t;
    size_t oi = (size_t)wid * (CC / 2) + lane;
    float2 hv = ((const float2*)x)[oi];
    xb[oi] = (f2bf_u(hv.y) << 16) | f2bf_u(hv.x);
    float2 wiv = *(const float2*)(wi + lane * 2);
    float2 wjv = *(const float2*)(wj + lane * 2);
    float a = hv.x * wiv.x + hv.y * wiv.y;
    float c = hv.x * wjv.x + hv.y * wjv.y;
#pragma unroll
    for (int o = 32; o > 0; o >>= 1) {
      a += __shfl_xor(a, o, 64);
      c += __shfl_xor(c, o, 64);
    }
    if (lane == 0) { pi[wid] = a; pjn[wid].x = c; }
  }
}

// ---- phase 2: per-HALF-partition (32 nodes) LDS bucket build + cnt-bounded
// dump + fused norms. 528 blocks (idx>=262 idle), 31KB LDS.
__global__ void k_bucket(const int* __restrict__ partCur, const unsigned int* __restrict__ partBuf,
                         int* __restrict__ cur_intra, int* __restrict__ cur_inter,
                         int* __restrict__ colS_intra, int* __restrict__ colS_inter,
                         float* __restrict__ dinv_intra, float* __restrict__ selfnorm,
                         float* __restrict__ dinv_inter, float2* __restrict__ pjn0) {
  __shared__ unsigned int sIn[32 * CAP2];
  __shared__ unsigned int sIt[32 * CAP2];
  __shared__ int sC[64];                     // [0..31] intra, [32..63] inter
  int tid = threadIdx.x;
  int xcd = blockIdx.x & 7;
  int b = xcd >> 2;
  int idx = (xcd & 3) * 66 + (blockIdx.x >> 3);
  if (idx >= 2 * P_B) return;                // block-uniform early out
  int p = idx >> 1;                          // partition within batch
  int half = idx & 1;                        // which 32-node half
  int gp = b * P_B + p;
  if (tid < 64) sC[tid] = 0;
  __syncthreads();
  int cnt = partCur[gp];
  cnt = cnt < CAPP ? cnt : CAPP;
  const unsigned int* buf = partBuf + (size_t)gp * CAPP;
  for (int i = tid; i < cnt; i += 256) {
    unsigned int v = buf[i];
    int off = (v >> 14) & 63;
    if ((off >> 5) != half) continue;
    int o = off & 31;
    int src = v & 0x3FFF;
    int dst = p * 64 + off;
    bool ss = (src < NODE_NUM) && (dst < NODE_NUM);
    bool tt = (src >= NODE_NUM) && (dst >= NODE_NUM);
    if (ss || tt) {
      int pos = atomicAdd(&sC[o], 1);
      if (pos < CAP2) sIn[o * CAP2 + pos] = src;
    } else {
      int pos = atomicAdd(&sC[32 + o], 1);
      if (pos < CAP2) sIt[o * CAP2 + pos] = src;
    }
  }
  __syncthreads();
  int dbase = p * 64 + half * 32;
  size_t gbase = ((size_t)b * NN + dbase) * CAP;
  for (int j = tid; j < 32 * CAP; j += 256) {
    int off = j >> 7, slot = j & (CAP - 1);
    int ci = sC[off];      ci = ci < CAP2 ? ci : CAP2;
    int ct = sC[32 + off]; ct = ct < CAP2 ? ct : CAP2;
    if (slot < ci) colS_intra[gbase + j] = (int)sIn[off * CAP2 + slot];
    if (slot < ct) colS_inter[gbase + j] = (int)sIt[off * CAP2 + slot];
  }
  if (tid < 32) {
    int node = b * NN + dbase + tid;
    int ci = sC[tid];       ci = ci < CAP2 ? ci : CAP2;
    int ct = sC[32 + tid];  ct = ct < CAP2 ? ct : CAP2;
    cur_intra[node] = ci;
    cur_inter[node] = ct;
    float df = (float)(ci + 1);             // gcn_norm adds a self loop
    float di = rsqrtf(df);
    dinv_intra[node] = di;
    selfnorm[node] = 1.0f / df;
    dinv_inter[node] = (ct > 0) ? (1.0f / (float)ct) : 0.0f;
    pjn0[node].y = di;                      // pair layer-1 pj with its src-norm
  }
}

// ---- gather: fused edge coefs, bf16 messages, readlane broadcast, 16-deep
//      load groups, PAIRED {pj,ns} random gather, fused next-layer proj ----
template <bool INTRA, bool RELU, bool NEXTPROJ, bool NEXT_INTRA>
__global__ void __launch_bounds__(256, 6)
k_gather(const float* __restrict__ h_in, const unsigned int* __restrict__ hm,
         float* __restrict__ h_out, unsigned int* __restrict__ hm_out,
         const int* __restrict__ cnt, const int* __restrict__ colS,
         const float* __restrict__ pi, const float2* __restrict__ pjn,
         const float* __restrict__ normD, const float* __restrict__ selfnorm,
         const float* __restrict__ dinv_intra,
         const float* __restrict__ nWi_s, const float* __restrict__ nWj_s,
         const float* __restrict__ nWi_t, const float* __restrict__ nWj_t,
         float* __restrict__ pi_out, float2* __restrict__ pjn_out) {
  int xcd = blockIdx.x & 7;
  int b = xcd >> 2;
  int u = (xcd & 3) * 524 + (blockIdx.x >> 3);
  int n = u * 4 + (threadIdx.x >> 6);
  int wid = b * NN + n;
  int lane = threadIdx.x & 63;
  int mt = cnt[wid];
  mt = mt < CAP ? mt : CAP;
  const float* hb = h_in + (size_t)b * NN * CC;
  const unsigned int* hmb = hm + (size_t)b * NN * (CC / 2) + lane;
  const float2* pjnb = pjn + b * NN;
  float p_i = pi[wid];
  float nd = normD[wid];
  const float2 hv = *(const float2*)(hb + (size_t)n * CC + lane * 2);
  float2 acc;
  if (INTRA) {
    // residual + self-loop message: h * (1 + tanh(pi+pj)/deg)  (fp32 path)
    float fac = 1.0f + tanhf(p_i + pjnb[n].x) * selfnorm[wid];
    acc.x = hv.x * fac;
    acc.y = hv.y * fac;
  } else {
    acc = hv;  // residual only
  }
  const int* cS = colS + (size_t)wid * CAP;
  for (int off = 0; off < mt; off += 64) {
    int rem = mt - off;
    int m = rem < 64 ? rem : 64;
    int src = 0;
    float c = 0.0f;
    if (lane < m) {
      src = cS[off + lane];
      float2 pn = pjnb[src];                 // one 8B random gather per edge
      float a = tanhf(p_i + pn.x);
      c = a * nd;
      if (INTRA) c *= pn.y;
    }
#pragma unroll
    for (int base = 0; base < 64; base += 16) {
      if (base >= m) break;
      unsigned int u16[16];
      float cj[16];
#pragma unroll
      for (int k = 0; k < 16; ++k) {
        int sj = __builtin_amdgcn_readlane(src, base + k);          // SGPR
        cj[k] = __int_as_float(
            __builtin_amdgcn_readlane(__float_as_int(c), base + k)); // SGPR
        u16[k] = hmb[sj * (CC / 2)];   // saddr-form load, 16 in flight
      }
#pragma unroll
      for (int k = 0; k < 16; ++k) {
        acc.x = fmaf(bf2f(u16[k] & 0xFFFFu), cj[k], acc.x);
        acc.y = fmaf(bf2f(u16[k] >> 16), cj[k], acc.y);
      }
    }
  }
  if (RELU) { acc.x = fmaxf(acc.x, 0.0f); acc.y = fmaxf(acc.y, 0.0f); }
  size_t oi = (size_t)wid * (CC / 2) + lane;
  *(float2*)(h_out + 2 * oi) = acc;
  if (NEXTPROJ) {
    hm_out[oi] = (f2bf_u(acc.y) << 16) | f2bf_u(acc.x);
    bool is_s = (n < NODE_NUM);
    const float* wi = is_s ? nWi_s : nWi_t;
    const float* wj = is_s ? nWj_s : nWj_t;
    float2 wiv = *(const float2*)(wi + lane * 2);
    float2 wjv = *(const float2*)(wj + lane * 2);
    float a = acc.x * wiv.x + acc.y * wiv.y;
    float c2 = acc.x * wjv.x + acc.y * wjv.y;
#pragma unroll
    for (int o = 32; o > 0; o >>= 1) {
      a += __shfl_xor(a, o, 64);
      c2 += __shfl_xor(c2, o, 64);
    }
    if (lane == 0) {
      pi_out[wid] = a;
      float2 pn;
      pn.x = c2;
      pn.y = NEXT_INTRA ? dinv_intra[wid] : 0.0f;
      pjn_out[wid] = pn;
    }
  }
}

extern "C" void kernel_launch(void* const* d_in, const int* in_sizes, int n_in,
                              void* d_out, int out_size, void* d_ws, size_t ws_size,
                              hipStream_t stream) {
  const float* x = (const float*)d_in[0];      // fp32 features [B,N,C]
  const int* ei = (const int*)d_in[1];         // int32 [B,2,E]
  const float* Wss = (const float*)d_in[2];    // fp32 [2, 2C]
  const float* Wtt = (const float*)d_in[3];
  const float* Wst = (const float*)d_in[4];
  const float* Wts = (const float*)d_in[5];
  float* out = (float*)d_out;                  // fp32 output [B,N,C]

  char* p = (char*)d_ws;
  auto alloc = [&](size_t bytes) {
    void* r = (void*)p;
    p += ((bytes + 255) & ~(size_t)255);
    return r;
  };
  float* h0 = (float*)alloc((size_t)BB * NN * CC * 4);
  float* h1 = (float*)alloc((size_t)BB * NN * CC * 4);
  unsigned int* xb = (unsigned int*)alloc((size_t)BB * NN * CC * 2);  // bf16 mirrors
  unsigned int* mb0 = (unsigned int*)alloc((size_t)BB * NN * CC * 2);
  unsigned int* mb1 = (unsigned int*)alloc((size_t)BB * NN * CC * 2);
  float* pi0 = (float*)alloc(BB * NN * 4);
  float* pi1 = (float*)alloc(BB * NN * 4);
  float2* pjn0 = (float2*)alloc(BB * NN * 8);   // paired {pj, src-norm}
  float2* pjn1 = (float2*)alloc(BB * NN * 8);
  float* dinv_intra = (float*)alloc(BB * NN * 4);
  float* selfnorm = (float*)alloc(BB * NN * 4);
  float* dinv_inter = (float*)alloc(BB * NN * 4);
  int* cur_intra = (int*)alloc(BB * NN * 4);
  int* cur_inter = (int*)alloc(BB * NN * 4);
  int* colS_intra = (int*)alloc((size_t)BB * NN * CAP * 4);  // 8.6 MB buckets
  int* colS_inter = (int*)alloc((size_t)BB * NN * CAP * 4);
  int* partCur = (int*)alloc(BB * P_B * 4);                  // 262 cursors
  unsigned int* partBuf = (unsigned int*)alloc((size_t)BB * P_B * CAPP * 4);  // 4.3 MB

  hipMemsetAsync(partCur, 0, BB * P_B * 4, stream);

  const int NODE_BLOCKS = (BB * NN * 64) / 256;  // 1 wave per node, 4 waves/block
  const float* wss0 = Wss, *wtt0 = Wtt, *wst0 = Wst, *wts0 = Wts;
  const float* wss1 = Wss + 256, *wtt1 = Wtt + 256, *wst1 = Wst + 256, *wts1 = Wts + 256;

  // phase 1 (edge partition) + init (pack x, layer-1 intra proj -> pi0/pjn0.x)
  k_part_init<<<FILLB + NODE_BLOCKS, 256, 0, stream>>>(
      ei, partCur, partBuf, x, xb, wss0, wss0 + 128, wtt0, wtt0 + 128, pi0, pjn0);
  // phase 2 (LDS bucket build, cnt-bounded dump, fused norms, pjn0.y)
  k_bucket<<<528, 256, 0, stream>>>(partCur, partBuf, cur_intra, cur_inter,
                                    colS_intra, colS_inter,
                                    dinv_intra, selfnorm, dinv_inter, pjn0);

  // layer 1 (intra, relu): (x,xb) -> (h0,mb0); fused proj for layer 2 (inter)
  // inter proj: s-node pi=W_ts[:C], pj=W_st[C:]; t-node pi=W_st[:C], pj=W_ts[C:]
  k_gather<true, true, true, false><<<NODE_BLOCKS, 256, 0, stream>>>(
      x, xb, h0, mb0, cur_intra, colS_intra, pi0, pjn0, dinv_intra, selfnorm, dinv_intra,
      wts0, wst0 + 128, wst0, wts0 + 128, pi1, pjn1);

  // layer 2 (inter, relu): (h0,mb0) -> (h1,mb1); fused proj for layer 3 (intra)
  k_gather<false, true, true, true><<<NODE_BLOCKS, 256, 0, stream>>>(
      h0, mb0, h1, mb1, cur_inter, colS_inter, pi1, pjn1, dinv_inter, selfnorm, dinv_intra,
      wss1, wss1 + 128, wtt1, wtt1 + 128, pi0, pjn0);

  // layer 3 (intra, relu): (h1,mb1) -> (h0,mb0); fused proj for layer 4 (inter)
  k_gather<true, true, true, false><<<NODE_BLOCKS, 256, 0, stream>>>(
      h1, mb1, h0, mb0, cur_intra, colS_intra, pi0, pjn0, dinv_intra, selfnorm, dinv_intra,
      wts1, wst1 + 128, wst1, wts1 + 128, pi1, pjn1);

  // layer 4 (inter, no relu): (h0,mb0) -> d_out; no next proj
  k_gather<false, false, false, false><<<NODE_BLOCKS, 256, 0, stream>>>(
      h0, mb0, out, nullptr, cur_inter, colS_inter, pi1, pjn1, dinv_inter, selfnorm,
      dinv_intra, nullptr, nullptr, nullptr, nullptr, nullptr, nullptr);
}